// Round 1
// baseline (1607.776 us; speedup 1.0000x reference)
//
#include <hip/hip_runtime.h>

// GCN forward, MI355X. Pipeline:
//   k1: y = x@W1  (fp32 tiled) -> split into y_hi/y_lo bf16, MFMA-B-frag-packed layout
//   k2: t = adj@y (bf16 MFMA 16x16x32, A staged fp32->bf16 via LDS, split-K x4, atomicAdd)
//   k3: p = relu(t+b1)@W2  (fp32, 2 cols)
//   k4: h2 = adj@p + b2, block-max, atomicMax on monotonic uint keys
//   k5: out = max0*W3[0] + max1*W3[1] + b3
// Floor: 2 adj reads = 2.15 GB ~= 341 us @ 6.3 TB/s.

#define NN 16384
#define NF 256
#define NH 64

typedef __attribute__((ext_vector_type(4))) float f32x4;
typedef __attribute__((ext_vector_type(2))) float f32x2;
typedef __attribute__((ext_vector_type(8))) short s16x8;

__device__ __forceinline__ unsigned short rne_bf16(float f) {
  unsigned int u = __builtin_bit_cast(unsigned int, f);
  unsigned int r = u + 0x7FFFu + ((u >> 16) & 1u);
  return (unsigned short)(r >> 16);
}

__device__ __forceinline__ s16x8 cvt_bf16x8(f32x4 u, f32x4 v) {
  s16x8 r;
  r[0] = (short)rne_bf16(u[0]); r[1] = (short)rne_bf16(u[1]);
  r[2] = (short)rne_bf16(u[2]); r[3] = (short)rne_bf16(u[3]);
  r[4] = (short)rne_bf16(v[0]); r[5] = (short)rne_bf16(v[1]);
  r[6] = (short)rne_bf16(v[2]); r[7] = (short)rne_bf16(v[3]);
  return r;
}

__device__ __forceinline__ unsigned int fkey(float f) {
  unsigned int b = __builtin_bit_cast(unsigned int, f);
  return (b & 0x80000000u) ? ~b : (b | 0x80000000u);
}

// ---------------- k1: y = x@W1, split hi/lo bf16, packed layout ----------------
// packed idx for element (row j, col c): (j>>3)*512 + c*8 + (j&7)   (ushort units)
__global__ __launch_bounds__(256)
void k1_xw1_split(const float* __restrict__ x, const float* __restrict__ w1,
                  unsigned short* __restrict__ yh, unsigned short* __restrict__ yl) {
  __shared__ float xsT[64][72];   // transposed x tile [k][m], padded (16B-aligned rows)
  __shared__ float wsm[64][68];   // W1 tile [k][n]
  const int t  = threadIdx.x;
  const int r0 = blockIdx.x * 64;
  const int rg = t >> 5;          // 0..7: 8-row group
  const int cg = t & 31;          // 0..31: 2-col group
  const int lm = t >> 2;          // load row 0..63
  const int lq = t & 3;           // load quarter

  float acc[8][2];
#pragma unroll
  for (int i = 0; i < 8; ++i) { acc[i][0] = 0.f; acc[i][1] = 0.f; }

  for (int kb = 0; kb < 4; ++kb) {
    const int kk = kb * 64;
    __syncthreads();
    const float* xp = x + (size_t)(r0 + lm) * NF + kk + lq * 16;
    f32x4 xa = *(const f32x4*)(xp);
    f32x4 xb = *(const f32x4*)(xp + 4);
    f32x4 xc = *(const f32x4*)(xp + 8);
    f32x4 xd = *(const f32x4*)(xp + 12);
    const float* wp = w1 + (size_t)(kk + lm) * NH + lq * 16;
    f32x4 wa = *(const f32x4*)(wp);
    f32x4 wb = *(const f32x4*)(wp + 4);
    f32x4 wc = *(const f32x4*)(wp + 8);
    f32x4 wd = *(const f32x4*)(wp + 12);
#pragma unroll
    for (int j = 0; j < 4; ++j) {
      xsT[lq * 16 + 0  + j][lm] = xa[j];
      xsT[lq * 16 + 4  + j][lm] = xb[j];
      xsT[lq * 16 + 8  + j][lm] = xc[j];
      xsT[lq * 16 + 12 + j][lm] = xd[j];
    }
    *(f32x4*)&wsm[lm][lq * 16 + 0]  = wa;
    *(f32x4*)&wsm[lm][lq * 16 + 4]  = wb;
    *(f32x4*)&wsm[lm][lq * 16 + 8]  = wc;
    *(f32x4*)&wsm[lm][lq * 16 + 12] = wd;
    __syncthreads();
#pragma unroll 8
    for (int k = 0; k < 64; ++k) {
      f32x4 a0 = *(const f32x4*)&xsT[k][rg * 8];
      f32x4 a1 = *(const f32x4*)&xsT[k][rg * 8 + 4];
      f32x2 wv = *(const f32x2*)&wsm[k][cg * 2];
#pragma unroll
      for (int j = 0; j < 4; ++j) {
        acc[j][0]     = fmaf(a0[j], wv[0], acc[j][0]);
        acc[j][1]     = fmaf(a0[j], wv[1], acc[j][1]);
        acc[4 + j][0] = fmaf(a1[j], wv[0], acc[4 + j][0]);
        acc[4 + j][1] = fmaf(a1[j], wv[1], acc[4 + j][1]);
      }
    }
  }
  // epilogue: double-bf16 split, packed 16B stores
  const int gr = r0 + rg * 8;
#pragma unroll
  for (int c = 0; c < 2; ++c) {
    const int gc = cg * 2 + c;
    s16x8 hv, lv;
#pragma unroll
    for (int i = 0; i < 8; ++i) {
      float yv = acc[i][c];
      unsigned short hb = rne_bf16(yv);
      float hf = __builtin_bit_cast(float, ((unsigned int)hb) << 16);
      unsigned short lb = rne_bf16(yv - hf);
      hv[i] = (short)hb;
      lv[i] = (short)lb;
    }
    const size_t idx = (size_t)(gr >> 3) * 512 + (size_t)gc * 8;
    *(s16x8*)(yh + idx) = hv;
    *(s16x8*)(yl + idx) = lv;
  }
}

// ---------------- k2: t += adj @ (y_hi + y_lo), split-K x4 ----------------
__global__ __launch_bounds__(256)
void k2_adjy(const float* __restrict__ adj, const unsigned short* __restrict__ yh,
             const unsigned short* __restrict__ yl, float* __restrict__ tbuf) {
  __shared__ unsigned short As[4096];  // 64x64 bf16, A-frag-packed: (k>>3)*512 + m*8 + (k&7)
  const int tid  = threadIdx.x;
  const int w    = tid >> 6;
  const int lane = tid & 63;
  const int bm   = blockIdx.x & 255;
  const int ks   = blockIdx.x >> 8;
  const int k0b  = ks * 4096;
  const int rw   = w & 1;       // wave row-half
  const int cwv  = w >> 1;      // wave col-half
  const int l15  = lane & 15, l4 = lane >> 4;

  // A staging: thread -> (row am, k-quarter aq)
  const int am = tid >> 2, aq = tid & 3;
  const float* ap = adj + (size_t)(bm * 64 + am) * NN + k0b + aq * 16;
  unsigned short* asw = As + aq * 1024 + am * 8;   // group g=2*aq

  const int mA0 = (rw * 32 + l15) * 8;
  const int mA1 = mA0 + 128;                        // +16 rows
  const int nB0 = (cwv * 32 + l15) * 8;
  const int nB1 = nB0 + 128;

  f32x4 acc00 = {0.f, 0.f, 0.f, 0.f};
  f32x4 acc01 = acc00, acc10 = acc00, acc11 = acc00;

  for (int it = 0; it < 64; ++it) {
    __syncthreads();
    const f32x4* a4 = (const f32x4*)(ap + it * 64);
    f32x4 a0 = a4[0], a1 = a4[1], a2 = a4[2], a3 = a4[3];
    *(s16x8*)(asw)       = cvt_bf16x8(a0, a1);
    *(s16x8*)(asw + 512) = cvt_bf16x8(a2, a3);
    __syncthreads();
    const int kg = ((k0b + it * 64) >> 3) + l4;
#pragma unroll
    for (int s = 0; s < 2; ++s) {
      const size_t bo = (size_t)(kg + s * 4) * 512;
      s16x8 bh0 = *(const s16x8*)(yh + bo + nB0);
      s16x8 bh1 = *(const s16x8*)(yh + bo + nB1);
      s16x8 bl0 = *(const s16x8*)(yl + bo + nB0);
      s16x8 bl1 = *(const s16x8*)(yl + bo + nB1);
      const int ao = (s * 4 + l4) * 512;
      s16x8 av0 = *(const s16x8*)(As + ao + mA0);
      s16x8 av1 = *(const s16x8*)(As + ao + mA1);
      acc00 = __builtin_amdgcn_mfma_f32_16x16x32_bf16(av0, bh0, acc00, 0, 0, 0);
      acc00 = __builtin_amdgcn_mfma_f32_16x16x32_bf16(av0, bl0, acc00, 0, 0, 0);
      acc01 = __builtin_amdgcn_mfma_f32_16x16x32_bf16(av0, bh1, acc01, 0, 0, 0);
      acc01 = __builtin_amdgcn_mfma_f32_16x16x32_bf16(av0, bl1, acc01, 0, 0, 0);
      acc10 = __builtin_amdgcn_mfma_f32_16x16x32_bf16(av1, bh0, acc10, 0, 0, 0);
      acc10 = __builtin_amdgcn_mfma_f32_16x16x32_bf16(av1, bl0, acc10, 0, 0, 0);
      acc11 = __builtin_amdgcn_mfma_f32_16x16x32_bf16(av1, bh1, acc11, 0, 0, 0);
      acc11 = __builtin_amdgcn_mfma_f32_16x16x32_bf16(av1, bl1, acc11, 0, 0, 0);
    }
  }
  // C/D layout (m89-verified): col = lane&15, row = (lane>>4)*4 + reg
  const int row0 = bm * 64 + rw * 32 + l4 * 4;
  const int col0 = cwv * 32 + l15;
#pragma unroll
  for (int i = 0; i < 4; ++i) {
    atomicAdd(&tbuf[(size_t)(row0 + i) * NH + col0],           acc00[i]);
    atomicAdd(&tbuf[(size_t)(row0 + i) * NH + col0 + 16],      acc01[i]);
    atomicAdd(&tbuf[(size_t)(row0 + 16 + i) * NH + col0],      acc10[i]);
    atomicAdd(&tbuf[(size_t)(row0 + 16 + i) * NH + col0 + 16], acc11[i]);
  }
}

// ---------------- k3: p = relu(t + b1) @ W2 ----------------
__global__ __launch_bounds__(256)
void k3_pw2(const float* __restrict__ tbuf, const float* __restrict__ b1,
            const float* __restrict__ w2, float* __restrict__ p0,
            float* __restrict__ p1) {
  const int t    = threadIdx.x;
  const int lane = t & 63;
  const int w    = t >> 6;
  const int sub  = lane >> 4;   // row within wave group of 4
  const int cl   = lane & 15;   // col quarter
  const int row  = blockIdx.x * 16 + w * 4 + sub;
  f32x4 tv = *(const f32x4*)(tbuf + (size_t)row * NH + cl * 4);
  f32x4 bv = *(const f32x4*)(b1 + cl * 4);
  float a0 = 0.f, a1 = 0.f;
#pragma unroll
  for (int j = 0; j < 4; ++j) {
    float h = tv[j] + bv[j];
    h = h > 0.f ? h : 0.f;
    f32x2 wv = *(const f32x2*)(w2 + (cl * 4 + j) * 2);
    a0 = fmaf(h, wv[0], a0);
    a1 = fmaf(h, wv[1], a1);
  }
#pragma unroll
  for (int m = 1; m <= 8; m <<= 1) {
    a0 += __shfl_xor(a0, m, 64);
    a1 += __shfl_xor(a1, m, 64);
  }
  if (cl == 0) { p0[row] = a0; p1[row] = a1; }
}

// ---------------- k4: h2 = adj@p + b2; block max; atomicMax keys ----------------
__global__ __launch_bounds__(256)
void k4_adjp(const float* __restrict__ adj, const float* __restrict__ p0,
             const float* __restrict__ p1, const float* __restrict__ b2,
             unsigned int* __restrict__ mk) {
  __shared__ float p0s[2048];
  __shared__ float p1s[2048];
  __shared__ float red0[32];
  __shared__ float red1[32];
  const int t = threadIdx.x;
  const size_t i0 = (size_t)blockIdx.x * 8;
  float ax[8], ay[8];
#pragma unroll
  for (int r = 0; r < 8; ++r) { ax[r] = 0.f; ay[r] = 0.f; }

  for (int ch = 0; ch < 8; ++ch) {
    const int c0 = ch * 2048;
    __syncthreads();
    ((f32x4*)p0s)[t]       = ((const f32x4*)(p0 + c0))[t];
    ((f32x4*)p0s)[t + 256] = ((const f32x4*)(p0 + c0))[t + 256];
    ((f32x4*)p1s)[t]       = ((const f32x4*)(p1 + c0))[t];
    ((f32x4*)p1s)[t + 256] = ((const f32x4*)(p1 + c0))[t + 256];
    __syncthreads();
    const f32x4 q0a = ((const f32x4*)p0s)[t];
    const f32x4 q0b = ((const f32x4*)p0s)[t + 256];
    const f32x4 q1a = ((const f32x4*)p1s)[t];
    const f32x4 q1b = ((const f32x4*)p1s)[t + 256];
#pragma unroll
    for (int r = 0; r < 8; ++r) {
      const float* arow = adj + (i0 + r) * NN + c0;
      const f32x4 aA = ((const f32x4*)arow)[t];
      const f32x4 aB = ((const f32x4*)arow)[t + 256];
#pragma unroll
      for (int j = 0; j < 4; ++j) {
        ax[r] = fmaf(aA[j], q0a[j], ax[r]);
        ax[r] = fmaf(aB[j], q0b[j], ax[r]);
        ay[r] = fmaf(aA[j], q1a[j], ay[r]);
        ay[r] = fmaf(aB[j], q1b[j], ay[r]);
      }
    }
  }
  const int lane = t & 63;
  const int w = t >> 6;
#pragma unroll
  for (int r = 0; r < 8; ++r) {
    float sx = ax[r], sy = ay[r];
#pragma unroll
    for (int m = 32; m >= 1; m >>= 1) {
      sx += __shfl_xor(sx, m, 64);
      sy += __shfl_xor(sy, m, 64);
    }
    if (lane == 0) { red0[w * 8 + r] = sx; red1[w * 8 + r] = sy; }
  }
  __syncthreads();
  if (t < 8) {
    float hx = red0[t] + red0[8 + t] + red0[16 + t] + red0[24 + t] + b2[0];
    float hy = red1[t] + red1[8 + t] + red1[16 + t] + red1[24 + t] + b2[1];
#pragma unroll
    for (int m = 4; m >= 1; m >>= 1) {
      hx = fmaxf(hx, __shfl_xor(hx, m, 64));
      hy = fmaxf(hy, __shfl_xor(hy, m, 64));
    }
    if (t == 0) {
      atomicMax(&mk[0], fkey(hx));
      atomicMax(&mk[1], fkey(hy));
    }
  }
}

// ---------------- k5: final linear ----------------
__global__ void k5_out(const unsigned int* __restrict__ mk, const float* __restrict__ w3,
                       const float* __restrict__ b3, float* __restrict__ out) {
  if (threadIdx.x == 0 && blockIdx.x == 0) {
    unsigned int u0 = mk[0], u1 = mk[1];
    unsigned int b0 = (u0 & 0x80000000u) ? (u0 & 0x7FFFFFFFu) : ~u0;
    unsigned int b1b = (u1 & 0x80000000u) ? (u1 & 0x7FFFFFFFu) : ~u1;
    float m0 = __builtin_bit_cast(float, b0);
    float m1 = __builtin_bit_cast(float, b1b);
    out[0] = m0 * w3[0] + m1 * w3[1] + b3[0];
  }
}

extern "C" void kernel_launch(void* const* d_in, const int* in_sizes, int n_in,
                              void* d_out, int out_size, void* d_ws, size_t ws_size,
                              hipStream_t stream) {
  const float* x   = (const float*)d_in[0];
  const float* adj = (const float*)d_in[1];
  const float* W1  = (const float*)d_in[2];
  const float* b1  = (const float*)d_in[3];
  const float* W2  = (const float*)d_in[4];
  const float* b2  = (const float*)d_in[5];
  const float* W3  = (const float*)d_in[6];
  const float* b3  = (const float*)d_in[7];

  char* ws = (char*)d_ws;
  // layout (all 256B-aligned): [mk 8B][t 4MB][yh 2MB][yl 2MB][p0 64KB][p1 64KB] ~= 8.2MB
  unsigned int*   mk = (unsigned int*)ws;
  float*          t  = (float*)(ws + 256);
  unsigned short* yh = (unsigned short*)(ws + 256 + 4194304);
  unsigned short* yl = (unsigned short*)(ws + 256 + 4194304 + 2097152);
  float*          p0 = (float*)(ws + 256 + 4194304 + 2 * 2097152);
  float*          p1 = (float*)(ws + 256 + 4194304 + 2 * 2097152 + 65536);

  hipMemsetAsync(mk, 0, 8, stream);                 // key 0 == -inf
  hipMemsetAsync(t, 0, (size_t)NN * NH * 4, stream); // split-K accum target

  k1_xw1_split<<<256, 256, 0, stream>>>(x, W1, yh, yl);
  k2_adjy<<<1024, 256, 0, stream>>>(adj, yh, yl, t);
  k3_pw2<<<1024, 256, 0, stream>>>(t, b1, W2, p0, p1);
  k4_adjp<<<2048, 256, 0, stream>>>(adj, p0, p1, b2, mk);
  k5_out<<<1, 64, 0, stream>>>(mk, W3, b3, (float*)d_out);
}